// Round 5
// baseline (175.408 us; speedup 1.0000x reference)
//
#include <hip/hip_runtime.h>
#include <math.h>

#define NBINS 1000
#define NDIM 64
#define DIMS_PER_BLOCK 8
#define DIM_GROUPS (NDIM / DIMS_PER_BLOCK)      // 8
#define BLOCK_THREADS 1024
#define ROWS_PER_ITER (BLOCK_THREADS / 2)       // 512 rows per block-iteration
#define ROW_BLOCKS 64                            // %8==0 -> same-XCD dim-groups;
                                                 // 512 blocks = 2/CU; 8 row-iters/block

typedef float floatx4 __attribute__((ext_vector_type(4)));  // native vec for nontemporal store

// zero the log_det region (re-poisoned 0xAA before every timed launch)
__global__ __launch_bounds__(1024) void mg_zero(float* __restrict__ p, int n) {
    int i = blockIdx.x * blockDim.x + threadIdx.x;
    if (i < n) p[i] = 0.0f;
}

// Block owns DIMS_PER_BLOCK dims; knots (x_i, c_i) staged in LDS (64 KB).
// Thread handles 4 dims of one row; 2 threads per row. 8-deep row loop with
// prefetched x gives MLP; log_det via one atomicAdd per thread-pair per row.
__global__ __launch_bounds__(BLOCK_THREADS, 8)
void mg_main(const float* __restrict__ x,
             const float* __restrict__ xvals,
             const float* __restrict__ cdf,
             float* __restrict__ out, int B) {
    __shared__ float2 knots[DIMS_PER_BLOCK * NBINS];   // 64000 B

    const int dimbase = blockIdx.y * DIMS_PER_BLOCK;

    // cooperative stage: coalesced reads of this block's 8-dim slice
    for (int k = threadIdx.x; k < DIMS_PER_BLOCK * NBINS; k += BLOCK_THREADS)
        knots[k] = make_float2(xvals[dimbase * NBINS + k], cdf[dimbase * NBINS + k]);
    __syncthreads();

    const int dl = (threadIdx.x & 1) * 4;                // local dims dl..dl+3
    const int qidx = blockIdx.y * 2 + (threadIdx.x & 1); // float4 index within row

    // per-dim seeds, hoisted out of the row loop
    float lo[4], invstep[4];
#pragma unroll
    for (int j = 0; j < 4; ++j) {
        float l = knots[(dl + j) * NBINS].x;
        float h = knots[(dl + j) * NBINS + NBINS - 1].x;
        lo[j] = l;
        invstep[j] = (float)(NBINS - 1) / (h - l);
    }

    const int rstride = gridDim.x * ROWS_PER_ITER;
    int row = blockIdx.x * ROWS_PER_ITER + (threadIdx.x >> 1);

    float4 xq = make_float4(0.f, 0.f, 0.f, 0.f);
    if (row < B) xq = ((const float4*)x)[(size_t)row * (NDIM / 4) + qidx];

    for (; row < B; row += rstride) {
        // prefetch next iteration's x before touching this row's data
        const int nrow = row + rstride;
        float4 xn = make_float4(0.f, 0.f, 0.f, 0.f);
        if (nrow < B) xn = ((const float4*)x)[(size_t)nrow * (NDIM / 4) + qidx];

        float xv[4] = {xq.x, xq.y, xq.z, xq.w};

        // seed indices, then all gathers issued together (ILP for LDS latency)
        int ii[4];
        float2 kl[4], kr[4];
#pragma unroll
        for (int j = 0; j < 4; ++j) {
            int i = (int)((xv[j] - lo[j]) * invstep[j]);   // trunc; clamp+walk fix
            ii[j] = min(max(i, 0), NBINS - 2);
        }
#pragma unroll
        for (int j = 0; j < 4; ++j) {
            kl[j] = knots[(dl + j) * NBINS + ii[j]];
            kr[j] = knots[(dl + j) * NBINS + ii[j] + 1];
        }

        float z4[4], ph[4], sumsq = 0.0f;
#pragma unroll
        for (int j = 0; j < 4; ++j) {
            int i = ii[j];
            float2 a = kl[j], b = kr[j];
            // exact searchsorted(side='left') fix-up walk (rarely taken)
            while (xv[j] > b.x && i < NBINS - 2) {
                ++i; a = b; b = knots[(dl + j) * NBINS + i + 1];
            }
            while (xv[j] <= a.x && i > 0) {
                --i; b = a; a = knots[(dl + j) * NBINS + i];
            }

            float denom = (b.x - a.x) + 1e-12f;
            float slope = (b.y - a.y) * __builtin_amdgcn_rcpf(denom);
            float u = fmaf(slope, xv[j] - a.x, a.y);
            ph[j] = fmaxf(slope, 1e-12f);
            u = fminf(fmaxf(u, 1e-6f), 1.0f - 1e-6f);
            float e1 = fminf(fmaxf(fmaf(2.0f, u, -1.0f), -0.99999f), 0.99999f);

            // Giles (2012) erfinv; tail poly wave-divergent (rare)
            float wv = -__logf(fmaf(-e1, e1, 1.0f));
            float t = wv - 2.5f;
            float p = 2.81022636e-08f;
            p = fmaf(p, t, 3.43273939e-07f);
            p = fmaf(p, t, -3.5233877e-06f);
            p = fmaf(p, t, -4.39150654e-06f);
            p = fmaf(p, t, 0.00021858087f);
            p = fmaf(p, t, -0.00125372503f);
            p = fmaf(p, t, -0.00417768164f);
            p = fmaf(p, t, 0.246640727f);
            p = fmaf(p, t, 1.50140941f);
            if (wv >= 5.0f) {
                float tq = sqrtf(wv) - 3.0f;
                float pt = -0.000200214257f;
                pt = fmaf(pt, tq, 0.000100950558f);
                pt = fmaf(pt, tq, 0.00134934322f);
                pt = fmaf(pt, tq, -0.00367342844f);
                pt = fmaf(pt, tq, 0.00573950773f);
                pt = fmaf(pt, tq, -0.0076224613f);
                pt = fmaf(pt, tq, 0.00943887047f);
                pt = fmaf(pt, tq, 1.00167406f);
                pt = fmaf(pt, tq, 2.83297682f);
                p = pt;
            }
            float z = 1.4142135623730951f * p * e1;
            z = fminf(fmaxf(z, -10.0f), 10.0f);
            z4[j] = z;
            sumsq = fmaf(z, z, sumsq);
        }

        floatx4 zv = {z4[0], z4[1], z4[2], z4[3]};
        __builtin_nontemporal_store(zv, (floatx4*)out + (size_t)row * (NDIM / 4) + qidx);

        // term = sum_j [log(p_hat_j) + 0.5 z^2 + log(sqrt(2pi))]
        // pairwise log products are safe: ph >= 1e-12 each -> product >= 1e-24.
        // -log(phi+1e-12) == 0.5 z^2 + 0.9189385 to 4.3e-8 abs since |z|<=4.417.
        float term = fmaf(0.5f, sumsq, 4.0f * 0.9189385332046727f)
                   + __logf(ph[0] * ph[1]) + __logf(ph[2] * ph[3]);

        term += __shfl_xor(term, 1, 64);   // partner lane covers the other 4 dims
        if ((threadIdx.x & 1) == 0)
            atomicAdd(out + (size_t)B * NDIM + row, term);

        xq = xn;
    }
}

extern "C" void kernel_launch(void* const* d_in, const int* in_sizes, int n_in,
                              void* d_out, int out_size, void* d_ws, size_t ws_size,
                              hipStream_t stream) {
    const float* x = (const float*)d_in[0];
    const float* xvals = (const float*)d_in[1];
    const float* cdf = (const float*)d_in[2];
    float* out = (float*)d_out;
    int B = in_sizes[0] / NDIM;

    hipLaunchKernelGGL(mg_zero, dim3((B + 1023) / 1024), dim3(1024), 0, stream,
                       out + (size_t)B * NDIM, B);
    hipLaunchKernelGGL(mg_main, dim3(ROW_BLOCKS, DIM_GROUPS), dim3(BLOCK_THREADS),
                       0, stream, x, xvals, cdf, out, B);
}

// Round 6
// 145.125 us; speedup vs baseline: 1.2087x; 1.2087x over previous
//
#include <hip/hip_runtime.h>
#include <math.h>

#define NBINS 1000
#define NDIM 64
#define DIMS_PER_BLOCK 8
#define DIM_GROUPS (NDIM / DIMS_PER_BLOCK)      // 8
#define BLOCK_THREADS 1024
#define ROWS_PER_ITER (BLOCK_THREADS / 2)       // 512 rows per block-iteration
#define ROW_BLOCKS 128                           // %8==0 -> same-XCD dim-groups;
                                                 // 1024 blocks = 2 sweeps of 2/CU

// zero the log_det region (atomic fallback path only)
__global__ __launch_bounds__(1024) void mg_zero(float* __restrict__ p, int n) {
    int i = blockIdx.x * blockDim.x + threadIdx.x;
    if (i < n) p[i] = 0.0f;
}

// final reduce: log_det[row] = sum over 8 dim-group partials in ws
__global__ __launch_bounds__(256) void mg_reduce(const float* __restrict__ ws,
                                                 float* __restrict__ out, int B) {
    int row = blockIdx.x * blockDim.x + threadIdx.x;
    if (row >= B) return;
    float s = 0.0f;
#pragma unroll
    for (int g = 0; g < DIM_GROUPS; ++g) s += ws[(size_t)g * B + row];
    out[row] = s;
}

// Block owns DIMS_PER_BLOCK dims; knots (x_i, c_i) staged in LDS (64 KB).
// Thread handles 4 dims of one row; 2 threads per row. Prefetched x for MLP.
// Partial log_det -> ws (coalesced), summed by mg_reduce. No atomics.
template <bool USE_WS>
__global__ __launch_bounds__(BLOCK_THREADS, 8)
void mg_main(const float* __restrict__ x,
             const float* __restrict__ xvals,
             const float* __restrict__ cdf,
             float* __restrict__ out, float* __restrict__ ws, int B) {
    __shared__ float2 knots[DIMS_PER_BLOCK * NBINS];   // 64000 B

    const int dimbase = blockIdx.y * DIMS_PER_BLOCK;

    for (int k = threadIdx.x; k < DIMS_PER_BLOCK * NBINS; k += BLOCK_THREADS)
        knots[k] = make_float2(xvals[dimbase * NBINS + k], cdf[dimbase * NBINS + k]);
    __syncthreads();

    const int dl = (threadIdx.x & 1) * 4;                // local dims dl..dl+3
    const int qidx = blockIdx.y * 2 + (threadIdx.x & 1); // float4 index within row

    float lo[4], invstep[4];
#pragma unroll
    for (int j = 0; j < 4; ++j) {
        float l = knots[(dl + j) * NBINS].x;
        float h = knots[(dl + j) * NBINS + NBINS - 1].x;
        lo[j] = l;
        invstep[j] = (float)(NBINS - 1) / (h - l);
    }

    const int rstride = gridDim.x * ROWS_PER_ITER;
    int row = blockIdx.x * ROWS_PER_ITER + (threadIdx.x >> 1);

    float4 xq = make_float4(0.f, 0.f, 0.f, 0.f);
    if (row < B) xq = ((const float4*)x)[(size_t)row * (NDIM / 4) + qidx];

    for (; row < B; row += rstride) {
        const int nrow = row + rstride;
        float4 xn = make_float4(0.f, 0.f, 0.f, 0.f);
        if (nrow < B) xn = ((const float4*)x)[(size_t)nrow * (NDIM / 4) + qidx];

        float xv[4] = {xq.x, xq.y, xq.z, xq.w};

        int ii[4];
        float2 kl[4], kr[4];
#pragma unroll
        for (int j = 0; j < 4; ++j) {
            int i = (int)((xv[j] - lo[j]) * invstep[j]);   // trunc; clamp+walk fix
            ii[j] = min(max(i, 0), NBINS - 2);
        }
#pragma unroll
        for (int j = 0; j < 4; ++j) {
            kl[j] = knots[(dl + j) * NBINS + ii[j]];
            kr[j] = knots[(dl + j) * NBINS + ii[j] + 1];
        }

        float z4[4], ph[4], sumsq = 0.0f;
#pragma unroll
        for (int j = 0; j < 4; ++j) {
            int i = ii[j];
            float2 a = kl[j], b = kr[j];
            // exact searchsorted(side='left') fix-up walk (rarely taken)
            while (xv[j] > b.x && i < NBINS - 2) {
                ++i; a = b; b = knots[(dl + j) * NBINS + i + 1];
            }
            while (xv[j] <= a.x && i > 0) {
                --i; b = a; a = knots[(dl + j) * NBINS + i];
            }

            float denom = (b.x - a.x) + 1e-12f;
            float slope = (b.y - a.y) * __builtin_amdgcn_rcpf(denom);
            float u = fmaf(slope, xv[j] - a.x, a.y);
            ph[j] = fmaxf(slope, 1e-12f);
            u = fminf(fmaxf(u, 1e-6f), 1.0f - 1e-6f);
            float e1 = fminf(fmaxf(fmaf(2.0f, u, -1.0f), -0.99999f), 0.99999f);

            // Giles (2012) erfinv; tail poly wave-divergent (rare)
            float wv = -__logf(fmaf(-e1, e1, 1.0f));
            float t = wv - 2.5f;
            float p = 2.81022636e-08f;
            p = fmaf(p, t, 3.43273939e-07f);
            p = fmaf(p, t, -3.5233877e-06f);
            p = fmaf(p, t, -4.39150654e-06f);
            p = fmaf(p, t, 0.00021858087f);
            p = fmaf(p, t, -0.00125372503f);
            p = fmaf(p, t, -0.00417768164f);
            p = fmaf(p, t, 0.246640727f);
            p = fmaf(p, t, 1.50140941f);
            if (wv >= 5.0f) {
                float tq = sqrtf(wv) - 3.0f;
                float pt = -0.000200214257f;
                pt = fmaf(pt, tq, 0.000100950558f);
                pt = fmaf(pt, tq, 0.00134934322f);
                pt = fmaf(pt, tq, -0.00367342844f);
                pt = fmaf(pt, tq, 0.00573950773f);
                pt = fmaf(pt, tq, -0.0076224613f);
                pt = fmaf(pt, tq, 0.00943887047f);
                pt = fmaf(pt, tq, 1.00167406f);
                pt = fmaf(pt, tq, 2.83297682f);
                p = pt;
            }
            float z = 1.4142135623730951f * p * e1;
            z = fminf(fmaxf(z, -10.0f), 10.0f);
            z4[j] = z;
            sumsq = fmaf(z, z, sumsq);
        }

        ((float4*)out)[(size_t)row * (NDIM / 4) + qidx] =
            make_float4(z4[0], z4[1], z4[2], z4[3]);

        // term = sum_j [log(p_hat_j) + 0.5 z^2 + log(sqrt(2pi))]
        // pairwise log products safe: ph >= 1e-12 each -> product >= 1e-24.
        // -log(phi+1e-12) == 0.5 z^2 + 0.9189385 to 4.3e-8 abs since |z|<=4.417.
        float term = fmaf(0.5f, sumsq, 4.0f * 0.9189385332046727f)
                   + __logf(ph[0] * ph[1]) + __logf(ph[2] * ph[3]);

        term += __shfl_xor(term, 1, 64);   // partner lane covers the other 4 dims
        if ((threadIdx.x & 1) == 0) {
            if constexpr (USE_WS)
                ws[(size_t)blockIdx.y * B + row] = term;   // coalesced partial
            else
                atomicAdd(out + (size_t)B * NDIM + row, term);
        }

        xq = xn;
    }
}

extern "C" void kernel_launch(void* const* d_in, const int* in_sizes, int n_in,
                              void* d_out, int out_size, void* d_ws, size_t ws_size,
                              hipStream_t stream) {
    const float* x = (const float*)d_in[0];
    const float* xvals = (const float*)d_in[1];
    const float* cdf = (const float*)d_in[2];
    float* out = (float*)d_out;
    int B = in_sizes[0] / NDIM;

    const size_t ws_need = (size_t)DIM_GROUPS * B * sizeof(float);
    dim3 grid(ROW_BLOCKS, DIM_GROUPS);

    if (ws_size >= ws_need) {
        float* ws = (float*)d_ws;
        hipLaunchKernelGGL((mg_main<true>), grid, dim3(BLOCK_THREADS), 0, stream,
                           x, xvals, cdf, out, ws, B);
        hipLaunchKernelGGL(mg_reduce, dim3((B + 255) / 256), dim3(256), 0, stream,
                           ws, out + (size_t)B * NDIM, B);
    } else {
        hipLaunchKernelGGL(mg_zero, dim3((B + 1023) / 1024), dim3(1024), 0, stream,
                           out + (size_t)B * NDIM, B);
        hipLaunchKernelGGL((mg_main<false>), grid, dim3(BLOCK_THREADS), 0, stream,
                           x, xvals, cdf, out, (float*)nullptr, B);
    }
}